// Round 1
// baseline (1218.692 us; speedup 1.0000x reference)
//
#include <hip/hip_runtime.h>
#include <math.h>

#define NBATCH 8
#define HGRID 128
#define DCH 256
#define NPTS 8192
#define INDIM 813
#define K0P 832
#define TOTROWS (NBATCH * NPTS)

__device__ __forceinline__ float gelu_f(float x) {
  float x3 = x * x * x;
  return 0.5f * x * (1.0f + tanhf(0.7978845608028654f * (x + 0.044715f * x3)));
}

// ---------------- ctx: gamma/beta ----------------
__global__ __launch_bounds__(256) void ctx_kernel(
    const float* __restrict__ cv, const float* __restrict__ cw,
    const float* __restrict__ cb, float* __restrict__ gb) {
  int b = blockIdx.x;
  int t = threadIdx.x;
  for (int half = 0; half < 2; ++half) {
    int j = half * 256 + t;
    float acc = cb[j];
    for (int k = 0; k < DCH; ++k)
      acc = fmaf(cv[b * DCH + k], cw[k * 512 + j], acc);
    if (j < 256) acc += 1.0f;  // gamma = ctx[:, :256] + 1
    gb[b * 512 + j] = acc;
  }
}

// ---------------- pad mlp0_w (813x256 -> 832x256, zero tail) ----------------
__global__ __launch_bounds__(256) void padw0_kernel(const float* __restrict__ w0,
                                                    float* __restrict__ w0p) {
  int idx = blockIdx.x * 256 + threadIdx.x;  // over K0P*256
  w0p[idx] = (idx < INDIM * 256) ? w0[idx] : 0.0f;
}

// ---------------- antialiased triangle resize weights (jax.image.resize) ----
template <int SCALE>
__device__ __forceinline__ void mkw(int o, int nIn, float* w, int* ix) {
  const int TAPS = 2 * SCALE;
  float s = (float)(SCALE * o) + 0.5f * (float)(SCALE - 1);  // (i+0.5)*S - 0.5
  int j0 = SCALE * o + (SCALE - 2) / 2 - (SCALE - 1);
  float wsum = 0.f;
#pragma unroll
  for (int t = 0; t < TAPS; ++t) {
    int j = j0 + t;
    float wt = 1.0f - fabsf(s - (float)j) * (1.0f / (float)SCALE);
    bool valid = (j >= 0) && (j < nIn);
    wt = valid ? wt : 0.0f;
    ix[t] = valid ? j : 0;
    w[t] = wt;
    wsum += wt;
  }
  float inv = 1.0f / wsum;
#pragma unroll
  for (int t = 0; t < TAPS; ++t) w[t] *= inv;
}

// ---------------- level downsample (separable product weights, 2D direct) ---
template <int SCALE>
__global__ __launch_bounds__(256) void level_kernel(const float* __restrict__ g,
                                                    float* __restrict__ out) {
  const int OW = HGRID / SCALE;
  int pix = (blockIdx.x << 2) + (threadIdx.x >> 6);
  int lane = threadIdx.x & 63;
  int b = pix / (OW * OW);
  int rem = pix - b * OW * OW;
  int oy = rem / OW, ox = rem - (rem / OW) * OW;
  float wy[2 * SCALE], wx[2 * SCALE];
  int iy[2 * SCALE], ix[2 * SCALE];
  mkw<SCALE>(oy, HGRID, wy, iy);
  mkw<SCALE>(ox, HGRID, wx, ix);
  float ax = 0.f, ay = 0.f, az = 0.f, aw = 0.f;
#pragma unroll
  for (int a = 0; a < 2 * SCALE; ++a) {
    if (wy[a] == 0.f) continue;
    const float* rowp = g + ((size_t)(b * HGRID + iy[a]) * HGRID) * DCH + lane * 4;
#pragma unroll
    for (int c = 0; c < 2 * SCALE; ++c) {
      float wgt = wy[a] * wx[c];
      if (wgt == 0.f) continue;
      const float4 v = *(const float4*)(rowp + (size_t)ix[c] * DCH);
      ax = fmaf(wgt, v.x, ax);
      ay = fmaf(wgt, v.y, ay);
      az = fmaf(wgt, v.z, az);
      aw = fmaf(wgt, v.w, aw);
    }
  }
  float4 r;
  r.x = ax; r.y = ay; r.z = az; r.w = aw;
  *(float4*)&out[(size_t)pix * DCH + lane * 4] = r;
}

// ---------------- bilinear sample of one level into h0 row -------------------
__device__ __forceinline__ void sample3(const float* __restrict__ g, int HW, int b,
                                        float cy, float cx, int lane,
                                        float* __restrict__ dst) {
  float fm = (float)(HW - 1);
  float y = ((cy + 1.0f) * 0.5f) * fm;
  float x = ((cx + 1.0f) * 0.5f) * fm;
  float y0f = fminf(fmaxf(floorf(y), 0.0f), fm);
  float x0f = fminf(fmaxf(floorf(x), 0.0f), fm);
  int y0 = (int)y0f, x0 = (int)x0f;
  int y1 = min(y0 + 1, HW - 1), x1 = min(x0 + 1, HW - 1);
  float wy = y - y0f, wx = x - x0f;
  size_t bb = (size_t)b * HW * HW;
  const float4 v00 = *(const float4*)&g[(bb + (size_t)y0 * HW + x0) * DCH + lane * 4];
  const float4 v01 = *(const float4*)&g[(bb + (size_t)y0 * HW + x1) * DCH + lane * 4];
  const float4 v10 = *(const float4*)&g[(bb + (size_t)y1 * HW + x0) * DCH + lane * 4];
  const float4 v11 = *(const float4*)&g[(bb + (size_t)y1 * HW + x1) * DCH + lane * 4];
  float t0 = v00.x * (1.f - wx) + v01.x * wx;
  float t1 = v00.y * (1.f - wx) + v01.y * wx;
  float t2 = v00.z * (1.f - wx) + v01.z * wx;
  float t3 = v00.w * (1.f - wx) + v01.w * wx;
  float b0 = v10.x * (1.f - wx) + v11.x * wx;
  float b1 = v10.y * (1.f - wx) + v11.y * wx;
  float b2 = v10.z * (1.f - wx) + v11.z * wx;
  float b3 = v10.w * (1.f - wx) + v11.w * wx;
  float r0 = t0 * (1.f - wy) + b0 * wy;
  float r1 = t1 * (1.f - wy) + b1 * wy;
  float r2 = t2 * (1.f - wy) + b2 * wy;
  float r3 = t3 * (1.f - wy) + b3 * wy;
  // dst offset is 2-float aligned only (42 + 4*lane): use float2 stores
  *(float2*)(dst + lane * 4) = make_float2(r0, r1);
  *(float2*)(dst + lane * 4 + 2) = make_float2(r2, r3);
}

// ---------------- assemble h0 row: [enc(42) | feats(768) | oracle(3) | pad] --
__global__ __launch_bounds__(256) void assemble_kernel(
    const float* __restrict__ g0, const float* __restrict__ g1,
    const float* __restrict__ g2, const float* __restrict__ coords,
    const float* __restrict__ oracle, float* __restrict__ h0, int row0, int nrows) {
  int lr = (blockIdx.x << 2) + (threadIdx.x >> 6);
  if (lr >= nrows) return;
  int lane = threadIdx.x & 63;
  int r = row0 + lr;
  int b = r >> 13, n = r & (NPTS - 1);
  float cy = coords[2 * n], cx = coords[2 * n + 1];
  float* row = h0 + (size_t)lr * K0P;
  if (lane < 2) {
    row[lane] = (lane == 0) ? cy : cx;
  } else if (lane < 42) {
    int q = lane - 2, f = q >> 2, m = q & 3;  // flatten: [freq][sin/cos][dim]
    float ang = ((m & 1) ? cx : cy) * ldexpf(3.14159274101257324f, f);
    row[lane] = (m < 2) ? sinf(ang) : cosf(ang);
  } else if (lane < 45) {
    row[810 + (lane - 42)] = oracle[((size_t)b * NPTS + n) * 3 + (lane - 42)];
  } else {
    row[INDIM + (lane - 45)] = 0.0f;  // lanes 45..63 zero pad 813..831
  }
  sample3(g0, 128, b, cy, cx, lane, row + 42);
  sample3(g1, 64, b, cy, cx, lane, row + 42 + 256);
  sample3(g2, 32, b, cy, cx, lane, row + 42 + 512);
}

// ---------------- fp32 GEMM + bias + FiLM + gelu -----------------------------
// C[r, n] = gelu((sum_k A[r,k] W[k,n] + bias[n]) * gamma[b,n] + beta[b,n])
__global__ __launch_bounds__(256, 2) void gemm_act(
    const float* __restrict__ A, int lda, int K, const float* __restrict__ W,
    const float* __restrict__ bias, const float* __restrict__ gb,
    float* __restrict__ C, int row0, int nrows) {
  __shared__ float As[32][132];  // [k][m], padded to 132 to spread banks
  __shared__ float Bs[32][128];  // [k][n]
  int tid = threadIdx.x;
  int tx = tid & 15, ty = tid >> 4;
  int m0 = blockIdx.x << 7;
  int n0 = blockIdx.y << 7;
  float acc[2][4][2][4];
#pragma unroll
  for (int ra = 0; ra < 2; ++ra)
#pragma unroll
    for (int i = 0; i < 4; ++i)
#pragma unroll
      for (int cbk = 0; cbk < 2; ++cbk)
#pragma unroll
        for (int j = 0; j < 4; ++j) acc[ra][i][cbk][j] = 0.f;

  for (int k0 = 0; k0 < K; k0 += 32) {
#pragma unroll
    for (int i = 0; i < 4; ++i) {
      int rr = (i << 5) + (tid >> 3);
      int cc = (tid & 7) << 2;
      int gr = m0 + rr;
      float4 v = make_float4(0.f, 0.f, 0.f, 0.f);
      if (gr < nrows) v = *(const float4*)&A[(size_t)gr * lda + k0 + cc];
      As[cc + 0][rr] = v.x;
      As[cc + 1][rr] = v.y;
      As[cc + 2][rr] = v.z;
      As[cc + 3][rr] = v.w;
    }
#pragma unroll
    for (int i = 0; i < 4; ++i) {
      int kr = (i << 3) + (tid >> 5);
      int cc = (tid & 31) << 2;
      *(float4*)&Bs[kr][cc] = *(const float4*)&W[(size_t)(k0 + kr) * 256 + n0 + cc];
    }
    __syncthreads();
#pragma unroll
    for (int kk = 0; kk < 32; ++kk) {
      float4 a0 = *(const float4*)&As[kk][ty << 2];
      float4 a1 = *(const float4*)&As[kk][64 + (ty << 2)];
      float4 b0 = *(const float4*)&Bs[kk][tx << 2];
      float4 b1 = *(const float4*)&Bs[kk][64 + (tx << 2)];
      float av[2][4] = {{a0.x, a0.y, a0.z, a0.w}, {a1.x, a1.y, a1.z, a1.w}};
      float bv[2][4] = {{b0.x, b0.y, b0.z, b0.w}, {b1.x, b1.y, b1.z, b1.w}};
#pragma unroll
      for (int ra = 0; ra < 2; ++ra)
#pragma unroll
        for (int i = 0; i < 4; ++i)
#pragma unroll
          for (int cbk = 0; cbk < 2; ++cbk)
#pragma unroll
            for (int j = 0; j < 4; ++j)
              acc[ra][i][cbk][j] = fmaf(av[ra][i], bv[cbk][j], acc[ra][i][cbk][j]);
    }
    __syncthreads();
  }
#pragma unroll
  for (int ra = 0; ra < 2; ++ra) {
#pragma unroll
    for (int i = 0; i < 4; ++i) {
      int m = (ra << 6) + (ty << 2) + i;
      int gr = m0 + m;
      if (gr >= nrows) continue;
      int bidx = (row0 + gr) >> 13;
      const float* gbb = gb + (bidx << 9);
#pragma unroll
      for (int cbk = 0; cbk < 2; ++cbk) {
        int n = n0 + (cbk << 6) + (tx << 2);
        float4 bi = *(const float4*)&bias[n];
        float4 ga = *(const float4*)&gbb[n];
        float4 be = *(const float4*)&gbb[256 + n];
        float4 r;
        r.x = gelu_f((acc[ra][i][cbk][0] + bi.x) * ga.x + be.x);
        r.y = gelu_f((acc[ra][i][cbk][1] + bi.y) * ga.y + be.y);
        r.z = gelu_f((acc[ra][i][cbk][2] + bi.z) * ga.z + be.z);
        r.w = gelu_f((acc[ra][i][cbk][3] + bi.w) * ga.w + be.w);
        *(float4*)&C[(size_t)gr * 256 + n] = r;
      }
    }
  }
}

// ---------------- final 256 -> 3 + tanh --------------------------------------
__global__ __launch_bounds__(256) void out_kernel(
    const float* __restrict__ Hb, const float* __restrict__ ow,
    const float* __restrict__ ob, float* __restrict__ out, int row0, int nrows) {
  int lr = (blockIdx.x << 2) + (threadIdx.x >> 6);
  if (lr >= nrows) return;
  int lane = threadIdx.x & 63;
  const float4 h = *(const float4*)&Hb[(size_t)lr * 256 + (lane << 2)];
  float hv[4] = {h.x, h.y, h.z, h.w};
  float s0 = 0.f, s1 = 0.f, s2 = 0.f;
#pragma unroll
  for (int j = 0; j < 4; ++j) {
    int k = (lane << 2) + j;
    s0 = fmaf(hv[j], ow[k * 3 + 0], s0);
    s1 = fmaf(hv[j], ow[k * 3 + 1], s1);
    s2 = fmaf(hv[j], ow[k * 3 + 2], s2);
  }
#pragma unroll
  for (int off = 32; off > 0; off >>= 1) {
    s0 += __shfl_down(s0, off);
    s1 += __shfl_down(s1, off);
    s2 += __shfl_down(s2, off);
  }
  if (lane == 0) {
    size_t r = (size_t)(row0 + lr);
    out[r * 3 + 0] = tanhf(s0 + ob[0]);
    out[r * 3 + 1] = tanhf(s1 + ob[1]);
    out[r * 3 + 2] = tanhf(s2 + ob[2]);
  }
}

extern "C" void kernel_launch(void* const* d_in, const int* in_sizes, int n_in,
                              void* d_out, int out_size, void* d_ws, size_t ws_size,
                              hipStream_t stream) {
  const float* feature_grid = (const float*)d_in[0];
  const float* context_vec = (const float*)d_in[1];
  const float* coords = (const float*)d_in[2];
  const float* oracle = (const float*)d_in[3];
  const float* mlp0_w = (const float*)d_in[4];
  const float* mlp0_b = (const float*)d_in[5];
  const float* mlp_hw = (const float*)d_in[6];
  const float* mlp_hb = (const float*)d_in[7];
  const float* ctx_w = (const float*)d_in[8];
  const float* ctx_b = (const float*)d_in[9];
  const float* out_w = (const float*)d_in[10];
  const float* out_b = (const float*)d_in[11];
  float* out = (float*)d_out;

  // ws layout: [gb 8x512][w0p 832x256][lvl1 8x64x64x256][lvl2 8x32x32x256][h0|hA|hB]
  float* gb = (float*)d_ws;
  float* w0p = gb + 8 * 512;
  float* lvl1 = w0p + (size_t)K0P * 256;
  float* lvl2 = lvl1 + (size_t)8 * 64 * 64 * 256;
  float* h0 = lvl2 + (size_t)8 * 32 * 32 * 256;
  size_t fixed_floats =
      (size_t)(8 * 512) + (size_t)K0P * 256 + (size_t)8 * 64 * 64 * 256 + (size_t)8 * 32 * 32 * 256;
  size_t per_row_floats = K0P + 512;
  long long cap = 0;
  if (ws_size / 4 > fixed_floats)
    cap = (long long)((ws_size / 4 - fixed_floats) / per_row_floats);
  if (cap > TOTROWS) cap = TOTROWS;
  cap &= ~127LL;
  if (cap < 128) cap = 128;
  float* hA = h0 + (size_t)cap * K0P;
  float* hB = hA + (size_t)cap * 256;

  hipLaunchKernelGGL(ctx_kernel, dim3(8), dim3(256), 0, stream, context_vec, ctx_w, ctx_b, gb);
  hipLaunchKernelGGL(padw0_kernel, dim3(K0P), dim3(256), 0, stream, mlp0_w, w0p);
  hipLaunchKernelGGL((level_kernel<2>), dim3(8 * 64 * 64 / 4), dim3(256), 0, stream,
                     feature_grid, lvl1);
  hipLaunchKernelGGL((level_kernel<4>), dim3(8 * 32 * 32 / 4), dim3(256), 0, stream,
                     feature_grid, lvl2);

  int npass = (int)((TOTROWS + cap - 1) / cap);
  for (int ps = 0; ps < npass; ++ps) {
    int row0 = (int)((long long)ps * cap);
    int nrows = TOTROWS - row0;
    if (nrows > cap) nrows = (int)cap;
    int pb = (nrows + 3) >> 2;
    hipLaunchKernelGGL(assemble_kernel, dim3(pb), dim3(256), 0, stream, feature_grid,
                       lvl1, lvl2, coords, oracle, h0, row0, nrows);
    dim3 ggrid((nrows + 127) >> 7, 2);
    hipLaunchKernelGGL(gemm_act, ggrid, dim3(256), 0, stream, h0, K0P, K0P, w0p,
                       mlp0_b, gb, hA, row0, nrows);
    hipLaunchKernelGGL(gemm_act, ggrid, dim3(256), 0, stream, hA, 256, 256,
                       mlp_hw + 0 * 65536, mlp_hb + 0, gb, hB, row0, nrows);
    hipLaunchKernelGGL(gemm_act, ggrid, dim3(256), 0, stream, hB, 256, 256,
                       mlp_hw + 1 * 65536, mlp_hb + 256, gb, hA, row0, nrows);
    hipLaunchKernelGGL(gemm_act, ggrid, dim3(256), 0, stream, hA, 256, 256,
                       mlp_hw + 2 * 65536, mlp_hb + 512, gb, hB, row0, nrows);
    hipLaunchKernelGGL(out_kernel, dim3(pb), dim3(256), 0, stream, hB, out_w, out_b,
                       out, row0, nrows);
  }
}

// Round 2
// 769.751 us; speedup vs baseline: 1.5832x; 1.5832x over previous
//
#include <hip/hip_runtime.h>
#include <math.h>
#include <stdint.h>

#define NBATCH 8
#define HGRID 128
#define DCH 256
#define NPTS 8192
#define INDIM 813
#define K0P 832
#define TOTROWS (NBATCH * NPTS)

typedef __attribute__((ext_vector_type(8))) short short8;
typedef __attribute__((ext_vector_type(16))) float f32x16;

// ---------- bf16 helpers ----------
__device__ __forceinline__ unsigned short bf16_rne(float f) {
  unsigned int u = __float_as_uint(f);
  u += 0x7fffu + ((u >> 16) & 1u);
  return (unsigned short)(u >> 16);
}
__device__ __forceinline__ float b2f(unsigned short h) {
  return __uint_as_float(((unsigned int)h) << 16);
}
__device__ __forceinline__ void split_bf16(float v, unsigned short& hi, unsigned short& lo) {
  hi = bf16_rne(v);
  lo = bf16_rne(v - b2f(hi));
}

__device__ __forceinline__ float gelu_f(float x) {
  float u = 0.7978845608028654f * (x + 0.044715f * x * x * x);
  float au = fabsf(u);
  float e = __expf(-2.0f * au);
  float t = 1.0f - 2.0f * e / (1.0f + e);
  t = copysignf(t, u);
  return 0.5f * x * (1.0f + t);
}

// ---------- async global->LDS 16B ----------
__device__ __forceinline__ void gload16(const void* g, void* l) {
  __builtin_amdgcn_global_load_lds(
      (const __attribute__((address_space(1))) unsigned int*)g,
      (__attribute__((address_space(3))) unsigned int*)l, 16, 0, 0);
}

// ---------------- ctx: gamma/beta ----------------
__global__ __launch_bounds__(256) void ctx_kernel(
    const float* __restrict__ cv, const float* __restrict__ cw,
    const float* __restrict__ cb, float* __restrict__ gb) {
  int b = blockIdx.x;
  int t = threadIdx.x;
  for (int half = 0; half < 2; ++half) {
    int j = half * 256 + t;
    float acc = cb[j];
    for (int k = 0; k < DCH; ++k)
      acc = fmaf(cv[b * DCH + k], cw[k * 512 + j], acc);
    if (j < 256) acc += 1.0f;
    gb[b * 512 + j] = acc;
  }
}

// ---------------- weight prep: transpose + split to bf16 hi/lo --------------
// w0t[n][k] (pitch 832) from mlp0_w[k][n], zero-pad k>=813
__global__ __launch_bounds__(256) void wprep0_kernel(const float* __restrict__ w0,
                                                     unsigned short* __restrict__ thi,
                                                     unsigned short* __restrict__ tlo) {
  int k = blockIdx.x;        // 0..831
  int n = threadIdx.x;       // 0..255
  float v = (k < INDIM) ? w0[(size_t)k * 256 + n] : 0.0f;
  unsigned short h, l;
  split_bf16(v, h, l);
  size_t o = (size_t)n * K0P + k;
  thi[o] = h; tlo[o] = l;
}
// wht[i][n][k] (pitch 256) from mlp_hw[i][k][n]
__global__ __launch_bounds__(256) void wpreph_kernel(const float* __restrict__ hw,
                                                     unsigned short* __restrict__ thi,
                                                     unsigned short* __restrict__ tlo) {
  int ik = blockIdx.x;       // i*256 + k
  int i = ik >> 8, k = ik & 255;
  int n = threadIdx.x;
  float v = hw[(size_t)ik * 256 + n];
  unsigned short h, l;
  split_bf16(v, h, l);
  size_t o = (size_t)i * 65536 + (size_t)n * 256 + k;
  thi[o] = h; tlo[o] = l;
}

// ---------------- antialiased triangle resize weights (jax.image.resize) ----
template <int SCALE>
__device__ __forceinline__ void mkw(int o, int nIn, float* w, int* ix) {
  const int TAPS = 2 * SCALE;
  float s = (float)(SCALE * o) + 0.5f * (float)(SCALE - 1);
  int j0 = SCALE * o + (SCALE - 2) / 2 - (SCALE - 1);
  float wsum = 0.f;
#pragma unroll
  for (int t = 0; t < TAPS; ++t) {
    int j = j0 + t;
    float wt = 1.0f - fabsf(s - (float)j) * (1.0f / (float)SCALE);
    bool valid = (j >= 0) && (j < nIn);
    wt = valid ? wt : 0.0f;
    ix[t] = valid ? j : 0;
    w[t] = wt;
    wsum += wt;
  }
  float inv = 1.0f / wsum;
#pragma unroll
  for (int t = 0; t < TAPS; ++t) w[t] *= inv;
}

// ---------------- separable resize: vertical then horizontal ----------------
// vpass: out[b][oy][x][c], oy < 128/SCALE, x < 128
template <int SCALE>
__global__ __launch_bounds__(256) void vpass_kernel(const float* __restrict__ g,
                                                    float* __restrict__ out) {
  const int HO = HGRID / SCALE;
  int pix = (blockIdx.x << 2) + (threadIdx.x >> 6);
  int lane = threadIdx.x & 63;
  int b = pix / (HO * HGRID);
  int rem = pix - b * (HO * HGRID);
  int oy = rem / HGRID, x = rem - (rem / HGRID) * HGRID;
  float wy[2 * SCALE]; int iy[2 * SCALE];
  mkw<SCALE>(oy, HGRID, wy, iy);
  float ax = 0.f, ay = 0.f, az = 0.f, aw = 0.f;
#pragma unroll
  for (int a = 0; a < 2 * SCALE; ++a) {
    if (wy[a] == 0.f) continue;
    const float4 v = *(const float4*)&g[((size_t)(b * HGRID + iy[a]) * HGRID + x) * DCH + lane * 4];
    ax = fmaf(wy[a], v.x, ax); ay = fmaf(wy[a], v.y, ay);
    az = fmaf(wy[a], v.z, az); aw = fmaf(wy[a], v.w, aw);
  }
  float4 r; r.x = ax; r.y = ay; r.z = az; r.w = aw;
  *(float4*)&out[(size_t)pix * DCH + lane * 4] = r;
}
// hpass: lvl[b][oy][ox][c] from v[b][oy][x 0..127][c]
template <int SCALE>
__global__ __launch_bounds__(256) void hpass_kernel(const float* __restrict__ v,
                                                    float* __restrict__ out) {
  const int HO = HGRID / SCALE, WO = HGRID / SCALE;
  int pix = (blockIdx.x << 2) + (threadIdx.x >> 6);
  int lane = threadIdx.x & 63;
  int b = pix / (HO * WO);
  int rem = pix - b * (HO * WO);
  int oy = rem / WO, ox = rem - (rem / WO) * WO;
  float wx[2 * SCALE]; int ix[2 * SCALE];
  mkw<SCALE>(ox, HGRID, wx, ix);
  float ax = 0.f, ay = 0.f, az = 0.f, aw = 0.f;
#pragma unroll
  for (int c = 0; c < 2 * SCALE; ++c) {
    if (wx[c] == 0.f) continue;
    const float4 t = *(const float4*)&v[((size_t)(b * HO + oy) * HGRID + ix[c]) * DCH + lane * 4];
    ax = fmaf(wx[c], t.x, ax); ay = fmaf(wx[c], t.y, ay);
    az = fmaf(wx[c], t.z, az); aw = fmaf(wx[c], t.w, aw);
  }
  float4 r; r.x = ax; r.y = ay; r.z = az; r.w = aw;
  *(float4*)&out[(size_t)pix * DCH + lane * 4] = r;
}

// ---------------- bilinear sample, split-bf16 write --------------------------
__device__ __forceinline__ void sample3(const float* __restrict__ g, int HW, int b,
                                        float cy, float cx, int lane,
                                        unsigned short* __restrict__ dhi,
                                        unsigned short* __restrict__ dlo) {
  float fm = (float)(HW - 1);
  float y = ((cy + 1.0f) * 0.5f) * fm;
  float x = ((cx + 1.0f) * 0.5f) * fm;
  float y0f = fminf(fmaxf(floorf(y), 0.0f), fm);
  float x0f = fminf(fmaxf(floorf(x), 0.0f), fm);
  int y0 = (int)y0f, x0 = (int)x0f;
  int y1 = min(y0 + 1, HW - 1), x1 = min(x0 + 1, HW - 1);
  float wy = y - y0f, wx = x - x0f;
  size_t bb = (size_t)b * HW * HW;
  const float4 v00 = *(const float4*)&g[(bb + (size_t)y0 * HW + x0) * DCH + lane * 4];
  const float4 v01 = *(const float4*)&g[(bb + (size_t)y0 * HW + x1) * DCH + lane * 4];
  const float4 v10 = *(const float4*)&g[(bb + (size_t)y1 * HW + x0) * DCH + lane * 4];
  const float4 v11 = *(const float4*)&g[(bb + (size_t)y1 * HW + x1) * DCH + lane * 4];
  float r[4];
  {
    float t0 = v00.x * (1.f - wx) + v01.x * wx, b0 = v10.x * (1.f - wx) + v11.x * wx;
    r[0] = t0 * (1.f - wy) + b0 * wy;
    float t1 = v00.y * (1.f - wx) + v01.y * wx, b1 = v10.y * (1.f - wx) + v11.y * wx;
    r[1] = t1 * (1.f - wy) + b1 * wy;
    float t2 = v00.z * (1.f - wx) + v01.z * wx, b2 = v10.z * (1.f - wx) + v11.z * wx;
    r[2] = t2 * (1.f - wy) + b2 * wy;
    float t3 = v00.w * (1.f - wx) + v01.w * wx, b3 = v10.w * (1.f - wx) + v11.w * wx;
    r[3] = t3 * (1.f - wy) + b3 * wy;
  }
  unsigned short h[4], l[4];
#pragma unroll
  for (int j = 0; j < 4; ++j) split_bf16(r[j], h[j], l[j]);
  ushort2 p;
  p.x = h[0]; p.y = h[1]; *(ushort2*)(dhi + lane * 4) = p;
  p.x = h[2]; p.y = h[3]; *(ushort2*)(dhi + lane * 4 + 2) = p;
  p.x = l[0]; p.y = l[1]; *(ushort2*)(dlo + lane * 4) = p;
  p.x = l[2]; p.y = l[3]; *(ushort2*)(dlo + lane * 4 + 2) = p;
}

// ---------------- assemble h0 row (split bf16 planes, pitch 832) ------------
__global__ __launch_bounds__(256) void assemble_kernel(
    const float* __restrict__ g0, const float* __restrict__ g1,
    const float* __restrict__ g2, const float* __restrict__ coords,
    const float* __restrict__ oracle, unsigned short* __restrict__ h0hi,
    unsigned short* __restrict__ h0lo, int row0, int nrows) {
  int lr = (blockIdx.x << 2) + (threadIdx.x >> 6);
  if (lr >= nrows) return;
  int lane = threadIdx.x & 63;
  int r = row0 + lr;
  int b = r >> 13, n = r & (NPTS - 1);
  float cy = coords[2 * n], cx = coords[2 * n + 1];
  unsigned short* rhi = h0hi + (size_t)lr * K0P;
  unsigned short* rlo = h0lo + (size_t)lr * K0P;
  if (lane < 45) {
    float val; int pos;
    if (lane < 2) { val = (lane == 0) ? cy : cx; pos = lane; }
    else if (lane < 42) {
      int q = lane - 2, f = q >> 2, m = q & 3;
      float ang = ((m & 1) ? cx : cy) * ldexpf(3.14159274101257324f, f);
      val = (m < 2) ? sinf(ang) : cosf(ang);
      pos = lane;
    } else { pos = 810 + (lane - 42); val = oracle[((size_t)b * NPTS + n) * 3 + (lane - 42)]; }
    unsigned short h, l; split_bf16(val, h, l);
    rhi[pos] = h; rlo[pos] = l;
  } else {
    int pos = INDIM + (lane - 45);  // 813..831
    rhi[pos] = 0; rlo[pos] = 0;
  }
  sample3(g0, 128, b, cy, cx, lane, rhi + 42, rlo + 42);
  sample3(g1, 64, b, cy, cx, lane, rhi + 42 + 256, rlo + 42 + 256);
  sample3(g2, 32, b, cy, cx, lane, rhi + 42 + 512, rlo + 42 + 512);
}

// ---------------- split-bf16 MFMA GEMM + bias + FiLM + gelu ------------------
// C[r,n] = gelu((sum_k A[r,k] W[k,n] + bias[n]) * gamma + beta), split-bf16 out
#define MFMA(a, b, c) __builtin_amdgcn_mfma_f32_32x32x16_bf16((a), (b), (c), 0, 0, 0)

__global__ __launch_bounds__(256) void gemm_mfma(
    const unsigned short* __restrict__ Ahi, const unsigned short* __restrict__ Alo, int lda,
    const unsigned short* __restrict__ Bhi, const unsigned short* __restrict__ Blo, int ldb,
    int K, const float* __restrict__ bias, const float* __restrict__ gb,
    unsigned short* __restrict__ Chi, unsigned short* __restrict__ Clo, int row0) {
  // LDS per plane: [rg 8][kc 4][ri 16][8 elems] = 8KB; planes: Ahi,Alo,Bhi,Blo
  __shared__ alignas(16) unsigned short lds[4][8][4][16][8];
  const int tid = threadIdx.x;
  const int lane = tid & 63;
  const int wid = tid >> 6;
  const int wm = wid >> 1, wn = wid & 1;
  const int m0 = blockIdx.x << 7;
  const int n0 = blockIdx.y << 7;
  const int ri = lane & 15;
  const int kc = lane >> 4;          // staging chunk 0..3
  const int rgbit = (lane >> 4) & 1; // frag row bit
  const int khalf = lane >> 5;       // frag k half

  // staging pointers: plane x {rg = wid*2, wid*2+1}
#define MKSRC(pl, baserow, pitch, jj) \
  ((pl) + (size_t)((baserow) + (wid * 2 + (jj)) * 16 + ri) * (pitch) + kc * 8)
  const unsigned short* sAh0 = MKSRC(Ahi, m0, lda, 0);
  const unsigned short* sAh1 = MKSRC(Ahi, m0, lda, 1);
  const unsigned short* sAl0 = MKSRC(Alo, m0, lda, 0);
  const unsigned short* sAl1 = MKSRC(Alo, m0, lda, 1);
  const unsigned short* sBh0 = MKSRC(Bhi, n0, ldb, 0);
  const unsigned short* sBh1 = MKSRC(Bhi, n0, ldb, 1);
  const unsigned short* sBl0 = MKSRC(Blo, n0, ldb, 0);
  const unsigned short* sBl1 = MKSRC(Blo, n0, ldb, 1);
  unsigned short* dAh0 = &lds[0][wid * 2 + 0][0][0][0];
  unsigned short* dAh1 = &lds[0][wid * 2 + 1][0][0][0];
  unsigned short* dAl0 = &lds[1][wid * 2 + 0][0][0][0];
  unsigned short* dAl1 = &lds[1][wid * 2 + 1][0][0][0];
  unsigned short* dBh0 = &lds[2][wid * 2 + 0][0][0][0];
  unsigned short* dBh1 = &lds[2][wid * 2 + 1][0][0][0];
  unsigned short* dBl0 = &lds[3][wid * 2 + 0][0][0][0];
  unsigned short* dBl1 = &lds[3][wid * 2 + 1][0][0][0];

  // frag read bases (element offsets; frag(mi,t) = base + mi*1024 + t*256)
  const unsigned short* Ah_base = &lds[0][wm * 4 + rgbit][khalf][ri][0];
  const unsigned short* Al_base = &lds[1][wm * 4 + rgbit][khalf][ri][0];
  const unsigned short* Bh_base = &lds[2][wn * 4 + rgbit][khalf][ri][0];
  const unsigned short* Bl_base = &lds[3][wn * 4 + rgbit][khalf][ri][0];

  f32x16 acc00 = {}, acc01 = {}, acc10 = {}, acc11 = {};

#pragma unroll 1
  for (int k0 = 0; k0 < K; k0 += 32) {
    gload16(sAh0, dAh0); gload16(sAh1, dAh1);
    gload16(sAl0, dAl0); gload16(sAl1, dAl1);
    gload16(sBh0, dBh0); gload16(sBh1, dBh1);
    gload16(sBl0, dBl0); gload16(sBl1, dBl1);
    sAh0 += 32; sAh1 += 32; sAl0 += 32; sAl1 += 32;
    sBh0 += 32; sBh1 += 32; sBl0 += 32; sBl1 += 32;
    __syncthreads();
#pragma unroll
    for (int t = 0; t < 2; ++t) {
      short8 ah0 = *(const short8*)(Ah_base + t * 256);
      short8 ah1 = *(const short8*)(Ah_base + 1024 + t * 256);
      short8 al0 = *(const short8*)(Al_base + t * 256);
      short8 al1 = *(const short8*)(Al_base + 1024 + t * 256);
      short8 bh0 = *(const short8*)(Bh_base + t * 256);
      short8 bh1 = *(const short8*)(Bh_base + 1024 + t * 256);
      short8 bl0 = *(const short8*)(Bl_base + t * 256);
      short8 bl1 = *(const short8*)(Bl_base + 1024 + t * 256);
      acc00 = MFMA(ah0, bh0, acc00);
      acc01 = MFMA(ah0, bh1, acc01);
      acc10 = MFMA(ah1, bh0, acc10);
      acc11 = MFMA(ah1, bh1, acc11);
      acc00 = MFMA(ah0, bl0, acc00);
      acc01 = MFMA(ah0, bl1, acc01);
      acc10 = MFMA(ah1, bl0, acc10);
      acc11 = MFMA(ah1, bl1, acc11);
      acc00 = MFMA(al0, bh0, acc00);
      acc01 = MFMA(al0, bh1, acc01);
      acc10 = MFMA(al1, bh0, acc10);
      acc11 = MFMA(al1, bh1, acc11);
    }
    __syncthreads();
  }

  const int bidx = (row0 + m0) >> 13;
  const float* gbb = gb + (bidx << 9);
  const int colbase = n0 + wn * 64 + (lane & 31);
  const int rowbase = m0 + wm * 64 + 4 * khalf;
#define EPI(accv, mi, ni)                                              \
  {                                                                    \
    int col = colbase + (ni)*32;                                       \
    float bi = bias[col], ga = gbb[col], be = gbb[256 + col];          \
    _Pragma("unroll") for (int rr = 0; rr < 16; ++rr) {                \
      int row = rowbase + (mi)*32 + (rr & 3) + ((rr >> 2) << 3);       \
      float v = (accv[rr] + bi) * ga + be;                             \
      v = gelu_f(v);                                                   \
      unsigned short h, l;                                             \
      split_bf16(v, h, l);                                             \
      size_t o = (size_t)row * 256 + col;                              \
      Chi[o] = h; Clo[o] = l;                                          \
    }                                                                  \
  }
  EPI(acc00, 0, 0)
  EPI(acc01, 0, 1)
  EPI(acc10, 1, 0)
  EPI(acc11, 1, 1)
}

// ---------------- final 256 -> 3 + tanh --------------------------------------
__global__ __launch_bounds__(256) void out_kernel(
    const unsigned short* __restrict__ Hhi, const unsigned short* __restrict__ Hlo,
    const float* __restrict__ ow, const float* __restrict__ ob,
    float* __restrict__ out, int row0, int nrows) {
  int lr = (blockIdx.x << 2) + (threadIdx.x >> 6);
  if (lr >= nrows) return;
  int lane = threadIdx.x & 63;
  size_t base = (size_t)lr * 256 + (lane << 2);
  ushort4 hh = *(const ushort4*)&Hhi[base];
  ushort4 ll = *(const ushort4*)&Hlo[base];
  float hv[4];
  hv[0] = b2f(hh.x) + b2f(ll.x);
  hv[1] = b2f(hh.y) + b2f(ll.y);
  hv[2] = b2f(hh.z) + b2f(ll.z);
  hv[3] = b2f(hh.w) + b2f(ll.w);
  float s0 = 0.f, s1 = 0.f, s2 = 0.f;
#pragma unroll
  for (int j = 0; j < 4; ++j) {
    int k = (lane << 2) + j;
    s0 = fmaf(hv[j], ow[k * 3 + 0], s0);
    s1 = fmaf(hv[j], ow[k * 3 + 1], s1);
    s2 = fmaf(hv[j], ow[k * 3 + 2], s2);
  }
#pragma unroll
  for (int off = 32; off > 0; off >>= 1) {
    s0 += __shfl_down(s0, off);
    s1 += __shfl_down(s1, off);
    s2 += __shfl_down(s2, off);
  }
  if (lane == 0) {
    size_t r = (size_t)(row0 + lr);
    out[r * 3 + 0] = tanhf(s0 + ob[0]);
    out[r * 3 + 1] = tanhf(s1 + ob[1]);
    out[r * 3 + 2] = tanhf(s2 + ob[2]);
  }
}

extern "C" void kernel_launch(void* const* d_in, const int* in_sizes, int n_in,
                              void* d_out, int out_size, void* d_ws, size_t ws_size,
                              hipStream_t stream) {
  const float* feature_grid = (const float*)d_in[0];
  const float* context_vec = (const float*)d_in[1];
  const float* coords = (const float*)d_in[2];
  const float* oracle = (const float*)d_in[3];
  const float* mlp0_w = (const float*)d_in[4];
  const float* mlp0_b = (const float*)d_in[5];
  const float* mlp_hw = (const float*)d_in[6];
  const float* mlp_hb = (const float*)d_in[7];
  const float* ctx_w = (const float*)d_in[8];
  const float* ctx_b = (const float*)d_in[9];
  const float* out_w = (const float*)d_in[10];
  const float* out_b = (const float*)d_in[11];
  float* out = (float*)d_out;

  // ---- workspace layout (bytes) ----
  char* p = (char*)d_ws;
  float* gb = (float*)p;                 p += 8 * 512 * 4;
  unsigned short* w0t_hi = (unsigned short*)p; p += (size_t)256 * K0P * 2;
  unsigned short* w0t_lo = (unsigned short*)p; p += (size_t)256 * K0P * 2;
  unsigned short* wht_hi = (unsigned short*)p; p += (size_t)3 * 65536 * 2;
  unsigned short* wht_lo = (unsigned short*)p; p += (size_t)3 * 65536 * 2;
  float* lvl1 = (float*)p;               p += (size_t)8 * 64 * 64 * 256 * 4;
  float* lvl2 = (float*)p;               p += (size_t)8 * 32 * 32 * 256 * 4;
  float* vtmp = (float*)p;               p += (size_t)8 * 64 * 128 * 256 * 4;
  size_t fixed_bytes = (size_t)(p - (char*)d_ws);
  size_t per_row_bytes = (size_t)K0P * 2 * 2 + (size_t)256 * 2 * 2 * 2;  // 5376
  long long cap = 0;
  if (ws_size > fixed_bytes) cap = (long long)((ws_size - fixed_bytes) / per_row_bytes);
  if (cap > TOTROWS) cap = TOTROWS;
  cap &= ~127LL;
  if (cap < 128) cap = 128;
  unsigned short* h0hi = (unsigned short*)p;
  unsigned short* h0lo = h0hi + (size_t)cap * K0P;
  unsigned short* hAhi = h0lo + (size_t)cap * K0P;
  unsigned short* hAlo = hAhi + (size_t)cap * 256;
  unsigned short* hBhi = hAlo + (size_t)cap * 256;
  unsigned short* hBlo = hBhi + (size_t)cap * 256;

  hipLaunchKernelGGL(ctx_kernel, dim3(8), dim3(256), 0, stream, context_vec, ctx_w, ctx_b, gb);
  hipLaunchKernelGGL(wprep0_kernel, dim3(K0P), dim3(256), 0, stream, mlp0_w, w0t_hi, w0t_lo);
  hipLaunchKernelGGL(wpreph_kernel, dim3(3 * 256), dim3(256), 0, stream, mlp_hw, wht_hi, wht_lo);
  // levels (separable, exact filter)
  hipLaunchKernelGGL((vpass_kernel<2>), dim3(8 * 64 * 128 / 4), dim3(256), 0, stream,
                     feature_grid, vtmp);
  hipLaunchKernelGGL((hpass_kernel<2>), dim3(8 * 64 * 64 / 4), dim3(256), 0, stream, vtmp, lvl1);
  hipLaunchKernelGGL((vpass_kernel<4>), dim3(8 * 32 * 128 / 4), dim3(256), 0, stream,
                     feature_grid, vtmp);
  hipLaunchKernelGGL((hpass_kernel<4>), dim3(8 * 32 * 32 / 4), dim3(256), 0, stream, vtmp, lvl2);

  int npass = (int)((TOTROWS + cap - 1) / cap);
  for (int ps = 0; ps < npass; ++ps) {
    int row0 = (int)((long long)ps * cap);
    int nrows = TOTROWS - row0;
    if (nrows > cap) nrows = (int)cap;
    int pb = (nrows + 3) >> 2;
    hipLaunchKernelGGL(assemble_kernel, dim3(pb), dim3(256), 0, stream, feature_grid,
                       lvl1, lvl2, coords, oracle, h0hi, h0lo, row0, nrows);
    dim3 ggrid(nrows >> 7, 2);
    hipLaunchKernelGGL(gemm_mfma, ggrid, dim3(256), 0, stream, h0hi, h0lo, K0P,
                       w0t_hi, w0t_lo, K0P, K0P, mlp0_b, gb, hAhi, hAlo, row0);
    hipLaunchKernelGGL(gemm_mfma, ggrid, dim3(256), 0, stream, hAhi, hAlo, 256,
                       wht_hi + 0 * 65536, wht_lo + 0 * 65536, 256, 256,
                       mlp_hb + 0, gb, hBhi, hBlo, row0);
    hipLaunchKernelGGL(gemm_mfma, ggrid, dim3(256), 0, stream, hBhi, hBlo, 256,
                       wht_hi + 1 * 65536, wht_lo + 1 * 65536, 256, 256,
                       mlp_hb + 256, gb, hAhi, hAlo, row0);
    hipLaunchKernelGGL(gemm_mfma, ggrid, dim3(256), 0, stream, hAhi, hAlo, 256,
                       wht_hi + 2 * 65536, wht_lo + 2 * 65536, 256, 256,
                       mlp_hb + 512, gb, hBhi, hBlo, row0);
    hipLaunchKernelGGL(out_kernel, dim3(pb), dim3(256), 0, stream, hBhi, hBlo,
                       out_w, out_b, out, row0, nrows);
  }
}